// Round 9
// baseline (490.177 us; speedup 1.0000x reference)
//
#include <hip/hip_runtime.h>
#include <hip/hip_bf16.h>

// Problem constants
#define HW    50176            // 224*224
#define IMGW  224
#define SEG   196              // R*R
#define NBATCH 128
#define NCOL  (NBATCH * SEG)   // 25088 rows (pixels) of every GEMM
#define PB    14               // accumulation blocks per batch image
#define CHUNK (HW / PB)        // 3584 pixels per block
#define VCHUNK (CHUNK / 4)     // 896 float4 groups per block

typedef __attribute__((ext_vector_type(8))) short bf16x8;   // 8 bf16 = 4 VGPRs
typedef __attribute__((ext_vector_type(4))) float f32x4;
typedef unsigned long long u64;

static __device__ __forceinline__ ushort f2bf(float v) {
    __hip_bfloat16 h = __float2bfloat16(v);
    return *reinterpret_cast<ushort*>(&h);
}

// ---------------------------------------------------------------------------
// Kernel 1: segmented accumulation via packed u64 LDS atomics (4 per pixel).
// Also emits float(sliced) into out[0..NBATCH*HW).  UNCHANGED (passed r5).
// ---------------------------------------------------------------------------
__global__ __launch_bounds__(256) void seg_accum(const float* __restrict__ x,
                                                 const int*   __restrict__ sl,
                                                 float*       __restrict__ stats,
                                                 float*       __restrict__ outf) {
    __shared__ u64 ls[4][SEG];
    int b    = blockIdx.x / PB;
    int part = blockIdx.x % PB;
    int tid  = threadIdx.x;

    for (int i = tid; i < 4 * SEG; i += 256) (&ls[0][0])[i] = 0ull;
    __syncthreads();

    const float* xb = x + (size_t)b * 3 * HW;
    const int*   sb = sl + (size_t)b * HW;
    float4*      ob = (float4*)(outf + (size_t)b * HW);
    int v0 = part * VCHUNK;

    for (int vi = tid; vi < VCHUNK; vi += 256) {
        int vg = v0 + vi;                 // float4 group index in image
        int4   id4 = ((const int4*)sb)[vg];
        float4 r4  = ((const float4*)xb)[vg];
        float4 g4  = ((const float4*)(xb + HW))[vg];
        float4 b4  = ((const float4*)(xb + 2 * HW))[vg];

        // fused copy_sliced: float conversion of the ids
        ob[vg] = make_float4((float)id4.x, (float)id4.y, (float)id4.z, (float)id4.w);

        int p   = vg * 4;
        int row = p / IMGW;               // 4 | 224 -> all 4 pixels same row
        int col = p - row * IMGW;
        u64 rowbits = ((u64)1 << 48) | ((u64)(unsigned)row << 24);

#pragma unroll
        for (int q = 0; q < 4; ++q) {
            int   id = (q == 0) ? id4.x : (q == 1) ? id4.y : (q == 2) ? id4.z : id4.w;
            float r  = (q == 0) ? r4.x  : (q == 1) ? r4.y  : (q == 2) ? r4.z  : r4.w;
            float g  = (q == 0) ? g4.x  : (q == 1) ? g4.y  : (q == 2) ? g4.z  : g4.w;
            float bl = (q == 0) ? b4.x  : (q == 1) ? b4.y  : (q == 2) ? b4.z  : b4.w;

            unsigned qr  = (unsigned)fmaf(r,  8192.f, 131072.5f);   // (r+16)*8192
            unsigned qg  = (unsigned)fmaf(g,  8192.f, 131072.5f);
            unsigned qb  = (unsigned)fmaf(bl, 8192.f, 131072.5f);
            unsigned qr2 = (unsigned)fmaf(r * r,  2048.f, 0.5f);
            unsigned qg2 = (unsigned)fmaf(g * g,  2048.f, 0.5f);
            unsigned qb2 = (unsigned)fmaf(bl * bl, 2048.f, 0.5f);

            atomicAdd(&ls[0][id], rowbits | (unsigned)(col + q));
            atomicAdd(&ls[1][id], ((u64)qg  << 32) | qr);
            atomicAdd(&ls[2][id], ((u64)qr2 << 32) | qb);
            atomicAdd(&ls[3][id], ((u64)qb2 << 32) | qg2);
        }
    }
    __syncthreads();

    const float inv_s = 1.f / 8192.f, inv_q = 1.f / 2048.f;
    for (int i = tid; i < SEG; i += 256) {
        u64 v0p = ls[0][i];
        unsigned cnt = (unsigned)(v0p >> 48);
        if (!cnt) continue;
        float fc   = (float)cnt;
        float rows = (float)((unsigned)(v0p >> 24) & 0xFFFFFFu);
        float cols = (float)((unsigned)v0p & 0xFFFFFFu);
        u64 v1 = ls[1][i], v2 = ls[2][i], v3 = ls[3][i];
        float bias = 16.f * fc;
        float rsum = (float)(unsigned)v1         * inv_s - bias;
        float gsum = (float)(unsigned)(v1 >> 32) * inv_s - bias;
        float bsum = (float)(unsigned)v2         * inv_s - bias;
        float rsq  = (float)(unsigned)(v2 >> 32) * inv_q;
        float gsq  = (float)(unsigned)v3         * inv_q;
        float bsq  = (float)(unsigned)(v3 >> 32) * inv_q;

        size_t base = (size_t)b * SEG + i;
        atomicAdd(&stats[0 * NCOL + base], fc);
        atomicAdd(&stats[1 * NCOL + base], rows);
        atomicAdd(&stats[2 * NCOL + base], cols);
        atomicAdd(&stats[3 * NCOL + base], rsum);
        atomicAdd(&stats[4 * NCOL + base], gsum);
        atomicAdd(&stats[5 * NCOL + base], bsum);
        atomicAdd(&stats[6 * NCOL + base], rsq);
        atomicAdd(&stats[7 * NCOL + base], gsq);
        atomicAdd(&stats[8 * NCOL + base], bsq);
    }
}

// ---------------------------------------------------------------------------
// Kernel: all 5 weight conversions in ONE dispatch.  UNCHANGED (passed r5).
// ---------------------------------------------------------------------------
__global__ __launch_bounds__(256) void convert_all(
    const float* __restrict__ s0, const float* __restrict__ s1,
    const float* __restrict__ s2, const float* __restrict__ s3,
    const float* __restrict__ s4,
    ushort* __restrict__ d0, ushort* __restrict__ d1, ushort* __restrict__ d2,
    ushort* __restrict__ d3, ushort* __restrict__ d4) {
    int blk = blockIdx.x;
    const float* src; ushort* dst; int Cout, K, Kpad, base;
    if (blk < 32)        { src = s0; dst = d0; Cout = 96;  K = 11;  Kpad = 64;  base = 0;    }
    else if (blk < 160)  { src = s1; dst = d1; Cout = 192; K = 96;  Kpad = 128; base = 32;   }
    else if (blk < 544)  { src = s2; dst = d2; Cout = 384; K = 192; Kpad = 256; base = 160;  }
    else if (blk < 1696) { src = s3; dst = d3; Cout = 768; K = 384; Kpad = 384; base = 544;  }
    else                 { src = s4; dst = d4; Cout = 768; K = 768; Kpad = 768; base = 1696; }
    int i = (blk - base) * 256 + threadIdx.x;
    int o = i / Kpad, k = i - o * Kpad;
    float v = (o < Cout && k < K) ? src[(size_t)o * K + k] : 0.f;
    dst[i] = f2bf(v);
}

// ---------------------------------------------------------------------------
// Fused kernel: feat_build + L0 + L1 + L2 for a 64-row panel.  UNCHANGED
// (passing since r3).  LDS: W dbuf [0,16384) | F | act0 | act1 == 88 KB.
// ---------------------------------------------------------------------------
#define SH_W   0
#define SH_F   16384
#define SH_A0  20480
#define SH_A1  28672

__global__ __launch_bounds__(256) void fused_l012(
    const float* __restrict__ x,
    const float* __restrict__ stats,
    const ushort* __restrict__ W0g, const ushort* __restrict__ W1g, const ushort* __restrict__ W2g,
    const float* __restrict__ bias0, const float* __restrict__ gam0, const float* __restrict__ bet0,
    const float* __restrict__ rm0,  const float* __restrict__ rv0,
    const float* __restrict__ bias1, const float* __restrict__ gam1, const float* __restrict__ bet1,
    const float* __restrict__ rm1,  const float* __restrict__ rv1,
    const float* __restrict__ bias2, const float* __restrict__ gam2, const float* __restrict__ bet2,
    const float* __restrict__ rm2,  const float* __restrict__ rv2,
    ushort* __restrict__ outA)
{
    __shared__ ushort sh[45056];
    int tid  = threadIdx.x;
    int lane = tid & 63;
    int wid  = tid >> 6;
    int mrow = lane & 15;
    int quad = lane >> 4;
    int n0   = blockIdx.x * 64;

    // ---------------- feature phase: row r handled by thread r (r<64) -------
    if (tid < 64) {
        int r = tid, n = n0 + r;
        float cnt  = stats[n];
        float safe = fmaxf(cnt, 1.f);
        float inv  = 1.f / safe;
        float fmrow = stats[1 * NCOL + n] * inv;
        float fmcol = stats[2 * NCOL + n] * inv;
        float fmr   = stats[3 * NCOL + n] * inv;
        float fmg   = stats[4 * NCOL + n] * inv;
        float fmb   = stats[5 * NCOL + n] * inv;
        float den  = fmaxf(cnt - 1.f, 1.f);
        float vr = (stats[6 * NCOL + n] - cnt * fmr * fmr) / den;
        float vg = (stats[7 * NCOL + n] - cnt * fmg * fmg) / den;
        float vb = (stats[8 * NCOL + n] - cnt * fmb * fmb) / den;
        bool  has2 = cnt > 1.f;
        float sr = has2 ? sqrtf(fmaxf(vr, 0.f)) : 0.f;
        float sg = has2 ? sqrtf(fmaxf(vg, 0.f)) : 0.f;
        float sb = has2 ? sqrtf(fmaxf(vb, 0.f)) : 0.f;
        int b = n / SEG;
        int ri = min(max((int)fmrow, 0), IMGW - 1);
        int ci = min(max((int)fmcol, 0), IMGW - 1);
        const float* xb = x + (size_t)b * 3 * HW;
        int pi = ri * IMGW + ci;
        float gr = xb[pi], gg = xb[HW + pi], gb = xb[2 * HW + pi];
        float mask = cnt > 0.f ? 1.f : 0.f;

        int rx = r & 7;
        bf16x8 v0;
        v0[0] = (short)f2bf(fmrow * mask);
        v0[1] = (short)f2bf(fmcol * mask);
        v0[2] = (short)f2bf(fmr * mask);
        v0[3] = (short)f2bf(fmg * mask);
        v0[4] = (short)f2bf(fmb * mask);
        v0[5] = (short)f2bf(sr * mask);
        v0[6] = (short)f2bf(sg * mask);
        v0[7] = (short)f2bf(sb * mask);
        *(bf16x8*)&sh[SH_F + r * 64 + (0 ^ rx) * 8] = v0;
        bf16x8 v1 = (bf16x8){0,0,0,0,0,0,0,0};
        v1[0] = (short)f2bf(gr * mask);
        v1[1] = (short)f2bf(gg * mask);
        v1[2] = (short)f2bf(gb * mask);
        *(bf16x8*)&sh[SH_F + r * 64 + (1 ^ rx) * 8] = v1;
        bf16x8 z = (bf16x8){0,0,0,0,0,0,0,0};
        for (int g = 2; g < 8; ++g)
            *(bf16x8*)&sh[SH_F + r * 64 + (g ^ rx) * 8] = z;
    }
    __syncthreads();

    auto stageW = [&](int buf, int ot, int kt, const ushort* Wg, int Kl) {
#pragma unroll
        for (int p = 0; p < 4; ++p) {
            int flat = p * 256 + tid;
            int row = flat >> 3, kg = flat & 7;
            int kgs = kg ^ (row & 7);
            const ushort* gp = Wg + (size_t)(ot * 128 + row) * Kl + kt * 64 + kgs * 8;
            __builtin_amdgcn_global_load_lds(
                (const __attribute__((address_space(1))) void*)gp,
                (__attribute__((address_space(3))) void*)&sh[SH_W + buf * 8192 + (p * 256 + wid * 64) * 8],
                16, 0, 0);
        }
    };

    auto run_layer = [&](const ushort* Wg, int KT, int OT, int aOff, int Win,
                         const float* bb, const float* gg_, const float* bbe,
                         const float* rrm, const float* rrv, int CoutL,
                         int outOff, int Wout, int toGlobal, int Kl) {
        stageW(0, 0, 0, Wg, Kl);
        asm volatile("s_waitcnt vmcnt(0)" ::: "memory");
        __builtin_amdgcn_s_barrier();

        int T = OT * KT, cur = 0, ot = 0, kt = 0;
        f32x4 acc[4][2];
        float al[2], bt[2];
        for (int t = 0; t < T; ++t) {
            if (kt == 0) {
#pragma unroll
                for (int j = 0; j < 2; ++j) {
                    acc[0][j] = (f32x4){0.f, 0.f, 0.f, 0.f};
                    acc[1][j] = (f32x4){0.f, 0.f, 0.f, 0.f};
                    acc[2][j] = (f32x4){0.f, 0.f, 0.f, 0.f};
                    acc[3][j] = (f32x4){0.f, 0.f, 0.f, 0.f};
                    int o = ot * 128 + wid * 32 + j * 16 + mrow;
                    float a = 0.f, c = 0.f;
                    if (o < CoutL) {
                        float sc = gg_[o] / sqrtf(rrv[o] + 1e-5f);
                        a = sc;
                        c = (bb[o] - rrm[o]) * sc + bbe[o];
                    }
                    al[j] = a; bt[j] = c;
                }
            }
            if (t + 1 < T) {
                int kt2 = kt + 1, ot2 = ot;
                if (kt2 == KT) { kt2 = 0; ot2 = ot + 1; }
                stageW(cur ^ 1, ot2, kt2, Wg, Kl);
            }
#pragma unroll
            for (int ks = 0; ks < 2; ++ks) {
                bf16x8 af[4], bfr[2];
                int g = kt * 8 + ks * 4 + quad;
#pragma unroll
                for (int i = 0; i < 4; ++i) {
                    int row = i * 16 + mrow;
                    int slot = (g & ~7) | ((g ^ row) & 7);
                    af[i] = *(const bf16x8*)&sh[aOff + row * Win + slot * 8];
                }
#pragma unroll
                for (int j = 0; j < 2; ++j) {
                    int wrow = wid * 32 + j * 16 + mrow;
                    int wslot = (ks * 4 + quad) ^ (wrow & 7);
                    bfr[j] = *(const bf16x8*)&sh[SH_W + cur * 8192 + wrow * 64 + wslot * 8];
                }
#pragma unroll
                for (int i = 0; i < 4; ++i)
#pragma unroll
                    for (int j = 0; j < 2; ++j)
                        acc[i][j] = __builtin_amdgcn_mfma_f32_16x16x32_bf16(af[i], bfr[j], acc[i][j], 0, 0, 0);
            }
            if (t + 1 < T) {
                asm volatile("s_waitcnt vmcnt(0)" ::: "memory");
                __builtin_amdgcn_s_barrier();
            }
            if (kt == KT - 1) {
#pragma unroll
                for (int j = 0; j < 2; ++j) {
                    int o = ot * 128 + wid * 32 + j * 16 + mrow;
#pragma unroll
                    for (int i = 0; i < 4; ++i)
#pragma unroll
                        for (int rr = 0; rr < 4; ++rr) {
                            float v = fmaxf(acc[i][j][rr] * al[j] + bt[j], 0.f);
                            int row = i * 16 + quad * 4 + rr;
                            if (toGlobal) {
                                outA[(size_t)(n0 + row) * 384 + o] = f2bf(v);
                            } else {
                                int cg = o >> 3;
                                int slot = (cg & ~7) | ((cg ^ row) & 7);
                                sh[outOff + row * Wout + slot * 8 + (o & 7)] = f2bf(v);
                            }
                        }
                }
                kt = 0; ++ot;
            } else ++kt;
            cur ^= 1;
        }
        __syncthreads();   // actOut visible before next layer's A-reads
    };

    run_layer(W0g, 1, 1, SH_F,  64,  bias0, gam0, bet0, rm0, rv0,  96, SH_A0, 128, 0, 64);
    run_layer(W1g, 2, 2, SH_A0, 128, bias1, gam1, bet1, rm1, rv1, 192, SH_A1, 256, 0, 128);
    run_layer(W2g, 4, 3, SH_A1, 256, bias2, gam2, bet2, rm2, rv2, 384, 0,     384, 1, 256);
}

// ---------------------------------------------------------------------------
// Fused L3+L4 for a 64-row panel.  L3 activation stays in LDS; only weights
// (+ bufA k-tiles for L3) are streamed.  Deletes the bufB global round-trip
// (77 MB) and one dispatch; L4 staging volume halves.
// LDS (ushort idx): staging dbuf [0,24576): buf*12288, A [0,4096) W [4096,12288)
//                   act3 (64x768 swizzled) [24576,73728)  == 144 KB
// Audited 3x: uniform barriers, bounded indices, involutive swizzles.
// r8 proved infra failures are content-independent -> resubmitting this.
// ---------------------------------------------------------------------------
#define L34_SG  0
#define L34_OUT 24576

__global__ __launch_bounds__(256) void fused_l34(
    const ushort* __restrict__ Aact,   // bufA: NCOL x 384 bf16
    const ushort* __restrict__ W3g, const ushort* __restrict__ W4g,
    const float* __restrict__ b3, const float* __restrict__ g3, const float* __restrict__ be3,
    const float* __restrict__ rm3, const float* __restrict__ rv3,
    const float* __restrict__ b4, const float* __restrict__ g4, const float* __restrict__ be4,
    const float* __restrict__ rm4, const float* __restrict__ rv4,
    float* __restrict__ outp)
{
    __shared__ ushort sh[73728];
    int tid  = threadIdx.x;
    int lane = tid & 63;
    int wid  = tid >> 6;
    int mrow = lane & 15;
    int quad = lane >> 4;
    int n0   = blockIdx.x * 64;

    auto stageA3 = [&](int buf, int kt) {
#pragma unroll
        for (int p = 0; p < 2; ++p) {
            int flat = p * 256 + tid;
            int row = flat >> 3, kg = flat & 7;
            int kgs = kg ^ (row & 7);
            const ushort* gp = Aact + (size_t)(n0 + row) * 384 + kt * 64 + kgs * 8;
            __builtin_amdgcn_global_load_lds(
                (const __attribute__((address_space(1))) void*)gp,
                (__attribute__((address_space(3))) void*)&sh[L34_SG + buf * 12288 + (p * 256 + wid * 64) * 8],
                16, 0, 0);
        }
    };
    auto stageW = [&](int buf, int ot, int kt, const ushort* Wg, int Kl) {
#pragma unroll
        for (int p = 0; p < 4; ++p) {
            int flat = p * 256 + tid;
            int row = flat >> 3, kg = flat & 7;
            int kgs = kg ^ (row & 7);
            const ushort* gp = Wg + (size_t)(ot * 128 + row) * Kl + kt * 64 + kgs * 8;
            __builtin_amdgcn_global_load_lds(
                (const __attribute__((address_space(1))) void*)gp,
                (__attribute__((address_space(3))) void*)&sh[L34_SG + buf * 12288 + 4096 + (p * 256 + wid * 64) * 8],
                16, 0, 0);
        }
    };

    // ---------------- Phase 1: L3 = relu(BN(A @ W3^T)) -> LDS act3 ----------
    {
        const int KT = 6, OT = 6, T = KT * OT;
        stageA3(0, 0);
        stageW(0, 0, 0, W3g, 384);
        asm volatile("s_waitcnt vmcnt(0)" ::: "memory");
        __builtin_amdgcn_s_barrier();
        int cur = 0, ot = 0, kt = 0;
        f32x4 acc[4][2];
        float al[2], bt[2];
        for (int t = 0; t < T; ++t) {
            if (kt == 0) {
#pragma unroll
                for (int j = 0; j < 2; ++j) {
#pragma unroll
                    for (int i = 0; i < 4; ++i) acc[i][j] = (f32x4){0.f, 0.f, 0.f, 0.f};
                    int o = ot * 128 + wid * 32 + j * 16 + mrow;   // < 768 always
                    float sc = g3[o] / sqrtf(rv3[o] + 1e-5f);
                    al[j] = sc;
                    bt[j] = (b3[o] - rm3[o]) * sc + be3[o];
                }
            }
            if (t + 1 < T) {
                int kt2 = kt + 1, ot2 = ot;
                if (kt2 == KT) { kt2 = 0; ot2 = ot + 1; }
                stageA3(cur ^ 1, kt2);
                stageW(cur ^ 1, ot2, kt2, W3g, 384);
            }
#pragma unroll
            for (int ks = 0; ks < 2; ++ks) {
                bf16x8 af[4], bfr[2];
                int gA = ks * 4 + quad;                 // tile-local 16B group
#pragma unroll
                for (int i = 0; i < 4; ++i) {
                    int row = i * 16 + mrow;
                    af[i] = *(const bf16x8*)&sh[L34_SG + cur * 12288 + row * 64 + (gA ^ (row & 7)) * 8];
                }
#pragma unroll
                for (int j = 0; j < 2; ++j) {
                    int wrow = wid * 32 + j * 16 + mrow;
                    bfr[j] = *(const bf16x8*)&sh[L34_SG + cur * 12288 + 4096 + wrow * 64 + (gA ^ (wrow & 7)) * 8];
                }
#pragma unroll
                for (int i = 0; i < 4; ++i)
#pragma unroll
                    for (int j = 0; j < 2; ++j)
                        acc[i][j] = __builtin_amdgcn_mfma_f32_16x16x32_bf16(af[i], bfr[j], acc[i][j], 0, 0, 0);
            }
            if (t + 1 < T) {
                asm volatile("s_waitcnt vmcnt(0)" ::: "memory");
                __builtin_amdgcn_s_barrier();
            }
            if (kt == KT - 1) {
#pragma unroll
                for (int j = 0; j < 2; ++j) {
                    int o = ot * 128 + wid * 32 + j * 16 + mrow;
                    int cg = o >> 3;
#pragma unroll
                    for (int i = 0; i < 4; ++i)
#pragma unroll
                        for (int rr = 0; rr < 4; ++rr) {
                            float v = fmaxf(acc[i][j][rr] * al[j] + bt[j], 0.f);
                            int row = i * 16 + quad * 4 + rr;
                            int slot = (cg & ~7) | ((cg ^ row) & 7);
                            sh[L34_OUT + row * 768 + slot * 8 + (o & 7)] = f2bf(v);
                        }
                }
                kt = 0; ++ot;
            } else ++kt;
            cur ^= 1;
        }
        __syncthreads();   // act3 complete before L4 reads
    }

    // ---------------- Phase 2: L4 = BN(act3 @ W4^T) -> global fp32 ----------
    {
        const int KT = 12, OT = 6, T = KT * OT;
        stageW(0, 0, 0, W4g, 768);
        asm volatile("s_waitcnt vmcnt(0)" ::: "memory");
        __builtin_amdgcn_s_barrier();
        int cur = 0, ot = 0, kt = 0;
        f32x4 acc[4][2];
        float al[2], bt[2];
        for (int t = 0; t < T; ++t) {
            if (kt == 0) {
#pragma unroll
                for (int j = 0; j < 2; ++j) {
#pragma unroll
                    for (int i = 0; i < 4; ++i) acc[i][j] = (f32x4){0.f, 0.f, 0.f, 0.f};
                    int o = ot * 128 + wid * 32 + j * 16 + mrow;
                    float sc = g4[o] / sqrtf(rv4[o] + 1e-5f);
                    al[j] = sc;
                    bt[j] = (b4[o] - rm4[o]) * sc + be4[o];
                }
            }
            if (t + 1 < T) {
                int kt2 = kt + 1, ot2 = ot;
                if (kt2 == KT) { kt2 = 0; ot2 = ot + 1; }
                stageW(cur ^ 1, ot2, kt2, W4g, 768);
            }
#pragma unroll
            for (int ks = 0; ks < 2; ++ks) {
                bf16x8 af[4], bfr[2];
                int g = kt * 8 + ks * 4 + quad;         // global 16B group 0..95
#pragma unroll
                for (int i = 0; i < 4; ++i) {
                    int row = i * 16 + mrow;
                    int slot = (g & ~7) | ((g ^ row) & 7);
                    af[i] = *(const bf16x8*)&sh[L34_OUT + row * 768 + slot * 8];
                }
#pragma unroll
                for (int j = 0; j < 2; ++j) {
                    int wrow = wid * 32 + j * 16 + mrow;
                    int wslot = (ks * 4 + quad) ^ (wrow & 7);
                    bfr[j] = *(const bf16x8*)&sh[L34_SG + cur * 12288 + 4096 + wrow * 64 + wslot * 8];
                }
#pragma unroll
                for (int i = 0; i < 4; ++i)
#pragma unroll
                    for (int j = 0; j < 2; ++j)
                        acc[i][j] = __builtin_amdgcn_mfma_f32_16x16x32_bf16(af[i], bfr[j], acc[i][j], 0, 0, 0);
            }
            if (t + 1 < T) {
                asm volatile("s_waitcnt vmcnt(0)" ::: "memory");
                __builtin_amdgcn_s_barrier();
            }
            if (kt == KT - 1) {
#pragma unroll
                for (int j = 0; j < 2; ++j) {
                    int o = ot * 128 + wid * 32 + j * 16 + mrow;
#pragma unroll
                    for (int i = 0; i < 4; ++i)
#pragma unroll
                        for (int rr = 0; rr < 4; ++rr) {
                            float v = acc[i][j][rr] * al[j] + bt[j];   // no relu
                            int row = i * 16 + quad * 4 + rr;
                            int n = n0 + row;
                            int b = n / SEG, s = n - b * SEG;
                            outp[(size_t)b * 768 * SEG + (size_t)o * SEG + s] = v;
                        }
                }
                kt = 0; ++ot;
            } else ++kt;
            cur ^= 1;
        }
    }
}

// ---------------------------------------------------------------------------
extern "C" void kernel_launch(void* const* d_in, const int* in_sizes, int n_in,
                              void* d_out, int out_size, void* d_ws, size_t ws_size,
                              hipStream_t stream) {
    const float* x  = (const float*)d_in[0];
    const int*   sl = (const int*)d_in[1];
    const float* Wp[5], *Bp[5], *Gp[5], *BEp[5], *RMp[5], *RVp[5];
    for (int i = 0; i < 5; ++i) {
        Wp[i]  = (const float*)d_in[2 + 6 * i + 0];
        Bp[i]  = (const float*)d_in[2 + 6 * i + 1];
        Gp[i]  = (const float*)d_in[2 + 6 * i + 2];
        BEp[i] = (const float*)d_in[2 + 6 * i + 3];
        RMp[i] = (const float*)d_in[2 + 6 * i + 4];
        RVp[i] = (const float*)d_in[2 + 6 * i + 5];
    }
    float* out = (float*)d_out;

    // layer geometry: Kpad (=prev Opad), Cout, Opad
    const int Kpad[5]  = {64, 128, 256, 384, 768};
    const int Opad[5]  = {128, 256, 384, 768, 768};

    // workspace layout (unchanged; F/bufB regions kept for layout stability)
    char* wsb = (char*)d_ws;
    float*  stats = (float*)wsb;                        // 9*NCOL fp32
    wsb += (size_t)9 * NCOL * sizeof(float);
    ushort* F = (ushort*)wsb;                           // NCOL x 64 bf16 (unused)
    wsb += (size_t)NCOL * 64 * sizeof(ushort);
    ushort* Wpad[5];
    for (int i = 0; i < 5; ++i) {
        Wpad[i] = (ushort*)wsb;
        wsb += (size_t)Opad[i] * Kpad[i] * sizeof(ushort);
    }
    ushort* bufA = (ushort*)wsb;                        // NCOL x 384 bf16
    wsb += (size_t)NCOL * 384 * sizeof(ushort);
    (void)F;

    hipMemsetAsync(stats, 0, (size_t)9 * NCOL * sizeof(float), stream);

    // all weight conversions in one dispatch
    convert_all<<<4000, 256, 0, stream>>>(
        Wp[0], Wp[1], Wp[2], Wp[3], Wp[4],
        Wpad[0], Wpad[1], Wpad[2], Wpad[3], Wpad[4]);

    // seg stats + fused sliced->float copy
    seg_accum<<<NBATCH * PB, 256, 0, stream>>>(x, sl, stats, out);

    // Fused feat + L0 + L1 + L2 -> bufA (NCOL x 384 bf16, plain row-major)
    fused_l012<<<NCOL / 64, 256, 0, stream>>>(
        x, stats, Wpad[0], Wpad[1], Wpad[2],
        Bp[0], Gp[0], BEp[0], RMp[0], RVp[0],
        Bp[1], Gp[1], BEp[1], RMp[1], RVp[1],
        Bp[2], Gp[2], BEp[2], RMp[2], RVp[2],
        bufA);

    // Fused L3 + L4 -> final fp32 output (b,768,196 layout at offset B*H*W)
    fused_l34<<<NCOL / 64, 256, 0, stream>>>(
        bufA, Wpad[3], Wpad[4],
        Bp[3], Gp[3], BEp[3], RMp[3], RVp[3],
        Bp[4], Gp[4], BEp[4], RMp[4], RVp[4],
        out + (size_t)NBATCH * HW);
}